// Round 1
// baseline (1475.082 us; speedup 1.0000x reference)
//
#include <hip/hip_runtime.h>
#include <hip/hip_bf16.h>

// Problem constants: query (B,Q,D), context (B,S,D)
constexpr int Bb = 256;
constexpr int Qq = 256;
constexpr int Ss = 512;
constexpr int Dd = 1024;

typedef __attribute__((ext_vector_type(8))) short short8;   // 8 x bf16 (4 VGPRs)
typedef __attribute__((ext_vector_type(4))) float floatx4;  // MFMA accumulator

typedef const __attribute__((address_space(1))) void* gas_ptr;
typedef __attribute__((address_space(3))) void* las_ptr;

__device__ __forceinline__ unsigned short f2b(float x) {
  return __builtin_bit_cast(unsigned short, __float2bfloat16(x));
}

__device__ __forceinline__ void gload_lds16(const void* g, void* l) {
  __builtin_amdgcn_global_load_lds((gas_ptr)g, (las_ptr)l, 16, 0, 0);
}

// ---------------------------------------------------------------------------
// K5: ctx fp32 [b][s][d] -> ctxT bf16 [b][d][s]   (64x64 LDS-tiled transpose)
// grid: B * (S/64) * (D/64) = 256*8*16 = 32768 blocks, 256 threads
// ---------------------------------------------------------------------------
__global__ __launch_bounds__(256) void ctx_tr_kernel(const float* __restrict__ ctx,
                                                     unsigned short* __restrict__ ctxT) {
  int bid = blockIdx.x;
  int b  = bid >> 7;
  int r  = bid & 127;
  int s0 = (r >> 4) * 64;
  int d0 = (r & 15) * 64;
  __shared__ float tile[64][65];
  int tx = threadIdx.x & 63;
  int ty = threadIdx.x >> 6;  // 0..3
  const float* base = ctx + (size_t)b * Ss * Dd + (size_t)s0 * Dd + d0;
  for (int k = 0; k < 16; ++k) {
    int sr = ty * 16 + k;
    tile[sr][tx] = base[(size_t)sr * Dd + tx];
  }
  __syncthreads();
  unsigned short* outp = ctxT + (size_t)b * Dd * Ss + (size_t)d0 * Ss + s0;
  for (int k = 0; k < 16; ++k) {
    int dr = ty * 16 + k;
    outp[(size_t)dr * Ss + tx] = f2b(tile[tx][dr]);
  }
}

// ---------------------------------------------------------------------------
// K1: attn[b][s][q] = leaky_relu( sum_d ctx[b][s][d]*qry[b][q][d] )
//     also row sum-of-squares partials ssPart[b][s][2] (one per q-halftile)
// grid: B * (S/128) * (Q/128) = 256*4*2 = 2048 blocks, 256 threads (4 waves)
// fp32 global -> cvt bf16 -> LDS staging; 128x128 tile; 16x16x32 bf16 MFMA
// ---------------------------------------------------------------------------
__global__ __launch_bounds__(256) void gemm1_kernel(const float* __restrict__ ctx,
                                                    const float* __restrict__ qry,
                                                    float* __restrict__ attn,
                                                    float* __restrict__ ssPart) {
  int bid = blockIdx.x;
  int b  = bid >> 3;
  int t  = bid & 7;
  int sm = (t >> 1) * 128;  // s tile base
  int qn = (t & 1) * 128;   // q tile base

  __shared__ unsigned short As[128 * 32];  // ctx tile  [s'][k] bf16
  __shared__ unsigned short Bs[128 * 32];  // qry tile  [q'][k] bf16
  __shared__ float ssbuf[128][2];

  int tid  = threadIdx.x;
  int lane = tid & 63;
  int w    = tid >> 6;
  int wm   = (w >> 1) * 64;
  int wn   = (w & 1) * 64;
  int quad = lane >> 4;
  int l15  = lane & 15;

  const float* Ag = ctx + (size_t)b * Ss * Dd + (size_t)sm * Dd;
  const float* Bg = qry + (size_t)b * Qq * Dd + (size_t)qn * Dd;

  floatx4 acc[4][4] = {};

  for (int k0 = 0; k0 < Dd; k0 += 32) {
    __syncthreads();
    // stage 128x32 fp32 -> bf16 for A and B
    for (int p = 0; p < 4; ++p) {
      int u   = tid + p * 256;        // float4 unit id, 0..1023
      int row = u >> 3;               // 0..127
      int col = (u & 7) << 2;         // 0..28
      float4 av = *(const float4*)(Ag + (size_t)row * Dd + k0 + col);
      float4 bv = *(const float4*)(Bg + (size_t)row * Dd + k0 + col);
      ushort4 a16, b16;
      a16.x = f2b(av.x); a16.y = f2b(av.y); a16.z = f2b(av.z); a16.w = f2b(av.w);
      b16.x = f2b(bv.x); b16.y = f2b(bv.y); b16.z = f2b(bv.z); b16.w = f2b(bv.w);
      *(ushort4*)(As + row * 32 + col) = a16;
      *(ushort4*)(Bs + row * 32 + col) = b16;
    }
    __syncthreads();
    short8 a[4], bb[4];
    for (int i = 0; i < 4; ++i)
      a[i] = *(const short8*)(As + (wm + i * 16 + l15) * 32 + quad * 8);
    for (int j = 0; j < 4; ++j)
      bb[j] = *(const short8*)(Bs + (wn + j * 16 + l15) * 32 + quad * 8);
    for (int i = 0; i < 4; ++i)
      for (int j = 0; j < 4; ++j)
        acc[i][j] = __builtin_amdgcn_mfma_f32_16x16x32_bf16(a[i], bb[j], acc[i][j], 0, 0, 0);
  }

  // epilogue: leaky relu, store, per-row sum of squares
  float* out = attn + (size_t)b * Ss * Qq + (size_t)sm * Qq + qn;
  for (int i = 0; i < 4; ++i) {
    for (int r = 0; r < 4; ++r) {
      int row = wm + i * 16 + quad * 4 + r;  // block-local s row
      float rowsum = 0.f;
      for (int j = 0; j < 4; ++j) {
        float v = acc[i][j][r];
        v = v > 0.f ? v : 0.1f * v;
        rowsum += v * v;
        out[(size_t)row * Qq + wn + j * 16 + l15] = v;
      }
      rowsum += __shfl_xor(rowsum, 1);
      rowsum += __shfl_xor(rowsum, 2);
      rowsum += __shfl_xor(rowsum, 4);
      rowsum += __shfl_xor(rowsum, 8);
      if (l15 == 0) ssbuf[row][w & 1] = rowsum;
    }
  }
  __syncthreads();
  if (tid < 128) {
    ssPart[((size_t)b * Ss + sm + tid) * 2 + (qn >> 7)] = ssbuf[tid][0] + ssbuf[tid][1];
  }
}

// ---------------------------------------------------------------------------
// K2: inv9[b][s] = 9 / (sqrt(ss) + 1e-8)
// ---------------------------------------------------------------------------
__global__ __launch_bounds__(256) void norm_kernel(const float* __restrict__ ssPart,
                                                   float* __restrict__ inv9) {
  int i = blockIdx.x * 256 + threadIdx.x;  // 0 .. B*S-1
  float ss = ssPart[2 * i] + ssPart[2 * i + 1];
  inv9[i] = 9.0f / (sqrtf(ss) + 1e-8f);
}

// ---------------------------------------------------------------------------
// K3: e = exp(attn * inv9[b][s]) in place; denom[b][q] += sum_s e (atomics)
// grid: B*4 blocks (128 s-rows each), 256 threads (one per q)
// ---------------------------------------------------------------------------
__global__ __launch_bounds__(256) void exp_kernel(float* __restrict__ attn,
                                                  const float* __restrict__ inv9,
                                                  float* __restrict__ denom) {
  int b  = blockIdx.x >> 2;
  int sc = (blockIdx.x & 3) * 128;
  int q  = threadIdx.x;
  float local = 0.f;
  float* base = attn + (size_t)b * Ss * Qq + (size_t)sc * Qq;
  const float* iv = inv9 + b * Ss + sc;
  for (int s = 0; s < 128; ++s) {
    float e = __expf(base[(size_t)s * Qq + q] * iv[s]);
    base[(size_t)s * Qq + q] = e;
    local += e;
  }
  atomicAdd(&denom[b * Qq + q], local);
}

// ---------------------------------------------------------------------------
// K4: p = e / denom; write back attnT (fp32, final output) and p_bf16 [b][q][s]
// grid: B * (S/64) * (Q/64) = 8192 blocks, 256 threads; 64x64 LDS transpose
// ---------------------------------------------------------------------------
__global__ __launch_bounds__(256) void div_tr_kernel(float* __restrict__ attn,
                                                     const float* __restrict__ denom,
                                                     unsigned short* __restrict__ pbf) {
  int bid = blockIdx.x;
  int b  = bid >> 5;
  int r  = bid & 31;
  int s0 = (r >> 2) * 64;
  int q0 = (r & 3) * 64;
  __shared__ float tile[64][65];
  int tx = threadIdx.x & 63;
  int ty = threadIdx.x >> 6;
  float rd = 1.0f / denom[b * Qq + q0 + tx];
  float* base = attn + (size_t)b * Ss * Qq + (size_t)s0 * Qq + q0;
  for (int k = 0; k < 16; ++k) {
    int sr = ty * 16 + k;
    float p = base[(size_t)sr * Qq + tx] * rd;
    base[(size_t)sr * Qq + tx] = p;
    tile[sr][tx] = p;
  }
  __syncthreads();
  unsigned short* outp = pbf + (size_t)b * Qq * Ss + (size_t)q0 * Ss + s0;
  for (int k = 0; k < 16; ++k) {
    int qr = ty * 16 + k;
    outp[(size_t)qr * Ss + tx] = f2b(tile[tx][qr]);
  }
}

// ---------------------------------------------------------------------------
// K6: weighted[b][q][d] = sum_s p[b][q][s] * ctxT[b][d][s]
// m97-style: global_load_lds width 16, 128x128 tile, BK=32, 4 waves
// grid: B * (Q/128) * (D/128) = 256*2*8 = 4096 blocks, 256 threads
// ---------------------------------------------------------------------------
__global__ __launch_bounds__(256) void gemm2_kernel(const unsigned short* __restrict__ pbf,
                                                    const unsigned short* __restrict__ ctxT,
                                                    float* __restrict__ outw) {
  int bid = blockIdx.x;
  int b  = bid >> 4;
  int t  = bid & 15;
  int m0 = (t >> 3) * 128;  // q tile base
  int n0 = (t & 7) * 128;   // d tile base

  __shared__ unsigned short As[128 * 32];  // p tile    [q'][k]
  __shared__ unsigned short Bs[128 * 32];  // ctxT tile [d'][k]

  int tid  = threadIdx.x;
  int lane = tid & 63;
  int w    = tid >> 6;
  int wm   = (w >> 1) * 64;
  int wn   = (w & 1) * 64;
  int quad = lane >> 4;
  int l15  = lane & 15;

  const unsigned short* Ag = pbf  + (size_t)b * Qq * Ss + (size_t)m0 * Ss;
  const unsigned short* Bg = ctxT + (size_t)b * Dd * Ss + (size_t)n0 * Ss;

  // staging map: lane L, chunk c: row = w*32 + c*16 + L/4, k elem offset (L&3)*8
  int rowA0 = w * 32 + (lane >> 2);
  int kofs  = (lane & 3) * 8;

  floatx4 acc[4][4] = {};

  for (int k0 = 0; k0 < Ss; k0 += 32) {
    __syncthreads();
    for (int c = 0; c < 2; ++c) {
      int row = rowA0 + c * 16;
      gload_lds16(Ag + (size_t)row * Ss + k0 + kofs, As + row * 32 + kofs);
      gload_lds16(Bg + (size_t)row * Ss + k0 + kofs, Bs + row * 32 + kofs);
    }
    __syncthreads();
    short8 a[4], bb[4];
    for (int i = 0; i < 4; ++i)
      a[i] = *(const short8*)(As + (wm + i * 16 + l15) * 32 + quad * 8);
    for (int j = 0; j < 4; ++j)
      bb[j] = *(const short8*)(Bs + (wn + j * 16 + l15) * 32 + quad * 8);
    for (int i = 0; i < 4; ++i)
      for (int j = 0; j < 4; ++j)
        acc[i][j] = __builtin_amdgcn_mfma_f32_16x16x32_bf16(a[i], bb[j], acc[i][j], 0, 0, 0);
  }

  float* out = outw + (size_t)b * Qq * Dd + (size_t)m0 * Dd + n0;
  for (int i = 0; i < 4; ++i)
    for (int r = 0; r < 4; ++r) {
      int row = wm + i * 16 + quad * 4 + r;
      for (int j = 0; j < 4; ++j)
        out[(size_t)row * Dd + wn + j * 16 + l15] = acc[i][j][r];
    }
}

// ---------------------------------------------------------------------------
extern "C" void kernel_launch(void* const* d_in, const int* in_sizes, int n_in,
                              void* d_out, int out_size, void* d_ws, size_t ws_size,
                              hipStream_t stream) {
  const float* qry = (const float*)d_in[0];   // (B,Q,D)
  const float* ctx = (const float*)d_in[1];   // (B,S,D)
  float* outw  = (float*)d_out;                           // (B,Q,D)
  float* attnT = outw + (size_t)Bb * Qq * Dd;             // (B,S,Q)

  char* ws = (char*)d_ws;
  // ws layout (bytes):
  //   ctxT bf16 [B][D][S] : 268435456
  //   p    bf16 [B][Q][S] :  67108864   @ 268435456
  //   ssPart fp32 [B][S][2]:  1048576   @ 335544320
  //   inv9  fp32 [B][S]   :    524288   @ 336592896
  //   denom fp32 [B][Q]   :    262144   @ 337117184
  unsigned short* ctxT = (unsigned short*)ws;
  unsigned short* pbf  = (unsigned short*)(ws + 268435456ull);
  float* ssPart = (float*)(ws + 335544320ull);
  float* inv9   = (float*)(ws + 336592896ull);
  float* denom  = (float*)(ws + 337117184ull);

  hipLaunchKernelGGL(ctx_tr_kernel, dim3(32768), dim3(256), 0, stream, ctx, ctxT);
  hipLaunchKernelGGL(gemm1_kernel,  dim3(2048),  dim3(256), 0, stream, ctx, qry, attnT, ssPart);
  hipLaunchKernelGGL(norm_kernel,   dim3(512),   dim3(256), 0, stream, ssPart, inv9);
  hipMemsetAsync(denom, 0, (size_t)Bb * Qq * sizeof(float), stream);
  hipLaunchKernelGGL(exp_kernel,    dim3(1024),  dim3(256), 0, stream, attnT, inv9, denom);
  hipLaunchKernelGGL(div_tr_kernel, dim3(8192),  dim3(256), 0, stream, attnT, denom, pbf);
  hipLaunchKernelGGL(gemm2_kernel,  dim3(4096),  dim3(256), 0, stream, pbf, ctxT, outw);
}